// Round 1
// baseline (130.697 us; speedup 1.0000x reference)
//
#include <hip/hip_runtime.h>
#include <hip/hip_bf16.h>
#include <stdint.h>

#define H 512
#define W 512
#define HW (H * W)

__device__ __forceinline__ int refl(int i, int n) {
    // BORDER_REFLECT_101: -1 -> 1, n -> n-2
    return i < 0 ? -i : (i >= n ? 2 * n - 2 - i : i);
}

// ---------------- K0: init min/max slots ----------------
__global__ void k_init(uint32_t* __restrict__ mnmx, int B) {
    int i = threadIdx.x;
    // layout: [src*B + b] * 2 + {0:min,1:max}
    for (; i < 2 * B; i += blockDim.x) {
        mnmx[2 * i + 0] = 0x7F800000u;  // +inf
        mnmx[2 * i + 1] = 0u;           // 0.0f (mag >= 0)
    }
}

// ---------------- K1: grayscale + uint8 quantize (both sources) ----------------
__global__ void k_gray(const float* __restrict__ vis, const float* __restrict__ ir,
                       uint8_t* __restrict__ qvis, uint8_t* __restrict__ qir, int B) {
    int tid = blockIdx.x * blockDim.x + threadIdx.x;
    int n4 = B * (HW / 4);
    const float* img;
    uint8_t* q;
    if (tid < n4) {
        img = vis; q = qvis;
    } else {
        tid -= n4;
        if (tid >= n4) return;
        img = ir; q = qir;
    }
    int b  = tid / (HW / 4);
    int i4 = tid % (HW / 4);
    const float4* p4 = (const float4*)(img + (size_t)b * 3 * HW);
    float4 r  = p4[i4];
    float4 g  = p4[i4 + (HW / 4)];
    float4 bl = p4[i4 + 2 * (HW / 4)];
    uchar4 o;
    o.x = (uint8_t)((0.2989f * r.x + 0.587f * g.x + 0.114f * bl.x) * 255.0f);
    o.y = (uint8_t)((0.2989f * r.y + 0.587f * g.y + 0.114f * bl.y) * 255.0f);
    o.z = (uint8_t)((0.2989f * r.z + 0.587f * g.z + 0.114f * bl.z) * 255.0f);
    o.w = (uint8_t)((0.2989f * r.w + 0.587f * g.w + 0.114f * bl.w) * 255.0f);
    *(uchar4*)(q + (size_t)b * HW + (size_t)i4 * 4) = o;
}

// ---------------- Sobel magnitude at (y,x), reflect-101 ----------------
__device__ __forceinline__ float sobel_mag(const uint8_t* __restrict__ q, int y, int x) {
    int ym = refl(y - 1, H) * W;
    int y0 = y * W;
    int yp = refl(y + 1, H) * W;
    int xm = refl(x - 1, W);
    int xp = refl(x + 1, W);
    float a00 = q[ym + xm], a01 = q[ym + x], a02 = q[ym + xp];
    float a10 = q[y0 + xm],                  a12 = q[y0 + xp];
    float a20 = q[yp + xm], a21 = q[yp + x], a22 = q[yp + xp];
    float gx = (a02 + 2.0f * a12 + a22) - (a00 + 2.0f * a10 + a20);
    float gy = (a20 + 2.0f * a21 + a22) - (a00 + 2.0f * a01 + a02);
    return sqrtf(gx * gx + gy * gy);
}

// ---------------- K2: per-image min/max of sobel magnitude ----------------
#define BPI 128  // blocks per image slice
__global__ void k_minmax(const uint8_t* __restrict__ qvis, const uint8_t* __restrict__ qir,
                         uint32_t* __restrict__ mnmx, int B) {
    int blk = blockIdx.x;
    int src = blk / (B * BPI);
    int rem = blk % (B * BPI);
    int b = rem / BPI;
    int chunk = rem % BPI;
    const uint8_t* q = (src ? qir : qvis) + (size_t)b * HW;
    int start = chunk * (HW / BPI);  // 2048 pixels per block
    float mn = INFINITY, mx = 0.0f;
    for (int j = 0; j < (HW / BPI); j += 256) {
        int i = start + j + threadIdx.x;
        int y = i >> 9, x = i & (W - 1);
        float m = sobel_mag(q, y, x);
        mn = fminf(mn, m);
        mx = fmaxf(mx, m);
    }
    // wave reduce (64 lanes)
    #pragma unroll
    for (int o = 32; o > 0; o >>= 1) {
        mn = fminf(mn, __shfl_down(mn, o));
        mx = fmaxf(mx, __shfl_down(mx, o));
    }
    __shared__ float smn[4], smx[4];
    int lane = threadIdx.x & 63, wid = threadIdx.x >> 6;
    if (lane == 0) { smn[wid] = mn; smx[wid] = mx; }
    __syncthreads();
    if (threadIdx.x == 0) {
        #pragma unroll
        for (int w = 1; w < 4; ++w) { mn = fminf(mn, smn[w]); mx = fmaxf(mx, smx[w]); }
        atomicMin(&mnmx[(src * B + b) * 2 + 0], __float_as_uint(mn));
        atomicMax(&mnmx[(src * B + b) * 2 + 1], __float_as_uint(mx));
    }
}

// ---------------- sobel for 4 consecutive x ----------------
__device__ __forceinline__ void sobel4(const uint8_t* __restrict__ q, int y, int x0,
                                       float* __restrict__ mag) {
    int ym = refl(y - 1, H) * W;
    int y0 = y * W;
    int yp = refl(y + 1, H) * W;
    float c0[6], c1[6], c2[6];
    #pragma unroll
    for (int j = 0; j < 6; ++j) {
        int x = refl(x0 - 1 + j, W);
        c0[j] = q[ym + x];
        c1[j] = q[y0 + x];
        c2[j] = q[yp + x];
    }
    #pragma unroll
    for (int k = 0; k < 4; ++k) {
        float gx = (c0[k + 2] + 2.0f * c1[k + 2] + c2[k + 2]) - (c0[k] + 2.0f * c1[k] + c2[k]);
        float gy = (c2[k] + 2.0f * c2[k + 1] + c2[k + 2]) - (c0[k] + 2.0f * c0[k + 1] + c0[k + 2]);
        mag[k] = sqrtf(gx * gx + gy * gy);
    }
}

// ---------------- K3: weighted blend + |diff| partial sums ----------------
__global__ void k_loss(const float* __restrict__ vis, const float* __restrict__ ir,
                       const float* __restrict__ fus,
                       const uint8_t* __restrict__ qvis, const uint8_t* __restrict__ qir,
                       const uint32_t* __restrict__ mnmx,
                       float* __restrict__ partial, int B) {
    int tid = blockIdx.x * 256 + threadIdx.x;   // one 4-pixel group per thread
    int i0 = tid * 4;                           // global pixel index in [0, B*HW)
    int b = i0 / HW;
    int i = i0 % HW;
    int y = i >> 9, x0 = i & (W - 1);

    float mn_v = __uint_as_float(mnmx[(0 * B + b) * 2 + 0]);
    float mx_v = __uint_as_float(mnmx[(0 * B + b) * 2 + 1]);
    float mn_i = __uint_as_float(mnmx[(1 * B + b) * 2 + 0]);
    float mx_i = __uint_as_float(mnmx[(1 * B + b) * 2 + 1]);
    float inv_v = 1.0f / fmaxf(mx_v - mn_v, 1e-8f);
    float inv_i = 1.0f / fmaxf(mx_i - mn_i, 1e-8f);

    float mv[4], mi[4];
    sobel4(qvis + (size_t)b * HW, y, x0, mv);
    sobel4(qir + (size_t)b * HW, y, x0, mi);

    float wv[4], wi[4];
    #pragma unroll
    for (int k = 0; k < 4; ++k) {
        float sv = (mv[k] - mn_v) * inv_v;
        float si = (mi[k] - mn_i) * inv_i;
        float den = sv + si + 1e-8f;
        wv[k] = sv / den;
        wi[k] = si / den;
    }

    float acc = 0.0f;
    #pragma unroll
    for (int ch = 0; ch < 3; ++ch) {
        size_t e4 = ((((size_t)b * 3 + ch) * HW) + i) >> 2;
        float4 v = ((const float4*)vis)[e4];
        float4 r = ((const float4*)ir)[e4];
        float4 f = ((const float4*)fus)[e4];
        acc += fabsf(wv[0] * v.x + wi[0] * r.x - f.x);
        acc += fabsf(wv[1] * v.y + wi[1] * r.y - f.y);
        acc += fabsf(wv[2] * v.z + wi[2] * r.z - f.z);
        acc += fabsf(wv[3] * v.w + wi[3] * r.w - f.w);
    }

    // block sum reduce
    #pragma unroll
    for (int o = 32; o > 0; o >>= 1) acc += __shfl_down(acc, o);
    __shared__ float ssum[4];
    int lane = threadIdx.x & 63, wid = threadIdx.x >> 6;
    if (lane == 0) ssum[wid] = acc;
    __syncthreads();
    if (threadIdx.x == 0) {
        acc = ssum[0] + ssum[1] + ssum[2] + ssum[3];
        partial[blockIdx.x] = acc;
    }
}

// ---------------- K4: final reduce ----------------
__global__ void k_final(const float* __restrict__ partial, int n, float* __restrict__ out,
                        long long N) {
    double s = 0.0;
    for (int i = threadIdx.x; i < n; i += 256) s += (double)partial[i];
    __shared__ double sm[256];
    sm[threadIdx.x] = s;
    __syncthreads();
    for (int k = 128; k > 0; k >>= 1) {
        if (threadIdx.x < k) sm[threadIdx.x] += sm[threadIdx.x + k];
        __syncthreads();
    }
    if (threadIdx.x == 0) out[0] = (float)(sm[0] / (double)N);
}

extern "C" void kernel_launch(void* const* d_in, const int* in_sizes, int n_in,
                              void* d_out, int out_size, void* d_ws, size_t ws_size,
                              hipStream_t stream) {
    const float* vis = (const float*)d_in[0];
    const float* ir  = (const float*)d_in[1];
    const float* fus = (const float*)d_in[2];
    int B = in_sizes[0] / (3 * HW);  // 16

    uint8_t* qvis = (uint8_t*)d_ws;
    uint8_t* qir  = qvis + (size_t)B * HW;
    uint32_t* mnmx = (uint32_t*)(qir + (size_t)B * HW);
    float* partial = (float*)(mnmx + 4 * B);
    float* out = (float*)d_out;

    k_init<<<1, 64, 0, stream>>>(mnmx, B);

    int n1 = 2 * B * (HW / 4);
    k_gray<<<(n1 + 255) / 256, 256, 0, stream>>>(vis, ir, qvis, qir, B);

    k_minmax<<<2 * B * BPI, 256, 0, stream>>>(qvis, qir, mnmx, B);

    int nblk3 = B * HW / 4 / 256;  // 4096
    k_loss<<<nblk3, 256, 0, stream>>>(vis, ir, fus, qvis, qir, mnmx, partial, B);

    k_final<<<1, 256, 0, stream>>>(partial, nblk3, out, (long long)B * 3 * HW);
}

// Round 2
// 117.689 us; speedup vs baseline: 1.1105x; 1.1105x over previous
//
#include <hip/hip_runtime.h>
#include <hip/hip_bf16.h>
#include <stdint.h>

#define H 512
#define W 512
#define HW (H * W)

__device__ __forceinline__ int refl(int i, int n) {
    // BORDER_REFLECT_101: -1 -> 1, n -> n-2
    return i < 0 ? -i : (i >= n ? 2 * n - 2 - i : i);
}

// Extract this lane's 10 stencil columns (x0-1 .. x0+8) as floats from an
// 8-byte row segment, halo bytes via wave shuffles. lane l owns x = l*8..l*8+7.
__device__ __forceinline__ void row_cols(uint2 v, int lane, float* __restrict__ c) {
    uint32_t lx = __shfl_up(v.y, 1);    // lane l-1's bytes x = l*8-4 .. l*8-1
    uint32_t rx = __shfl_down(v.x, 1);  // lane l+1's bytes x = l*8+8 .. l*8+11
    uint32_t lb = (lane == 0)  ? ((v.x >> 8) & 0xffu)  : (lx >> 24);      // x=-1 -> x=1
    uint32_t rb = (lane == 63) ? ((v.y >> 16) & 0xffu) : (rx & 0xffu);    // x=512 -> x=510
    c[0] = (float)lb;
    c[1] = (float)(v.x & 0xffu);
    c[2] = (float)((v.x >> 8) & 0xffu);
    c[3] = (float)((v.x >> 16) & 0xffu);
    c[4] = (float)(v.x >> 24);
    c[5] = (float)(v.y & 0xffu);
    c[6] = (float)((v.y >> 8) & 0xffu);
    c[7] = (float)((v.y >> 16) & 0xffu);
    c[8] = (float)(v.y >> 24);
    c[9] = (float)rb;
}

// 8 sobel magnitudes for lane's pixels in row y; q = image base.
__device__ __forceinline__ void sobel_row8(const uint8_t* __restrict__ q, int y, int lane,
                                           float* __restrict__ mag) {
    const uint2* rm = (const uint2*)(q + (size_t)refl(y - 1, H) * W);
    const uint2* r0 = (const uint2*)(q + (size_t)y * W);
    const uint2* rp = (const uint2*)(q + (size_t)refl(y + 1, H) * W);
    uint2 vm = rm[lane], v0 = r0[lane], vp = rp[lane];
    float c0[10], c1[10], c2[10];
    row_cols(vm, lane, c0);
    row_cols(v0, lane, c1);
    row_cols(vp, lane, c2);
    float sx[10], sy[10];
    #pragma unroll
    for (int j = 0; j < 10; ++j) {
        sx[j] = c0[j] + 2.0f * c1[j] + c2[j];  // [1,2,1] down the rows
        sy[j] = c2[j] - c0[j];
    }
    #pragma unroll
    for (int k = 0; k < 8; ++k) {
        float gx = sx[k + 2] - sx[k];
        float gy = sy[k] + 2.0f * sy[k + 1] + sy[k + 2];
        mag[k] = sqrtf(gx * gx + gy * gy);
    }
}

// ---------------- K0: init min/max slots ----------------
__global__ void k_init(uint32_t* __restrict__ mnmx, int B) {
    int i = threadIdx.x;
    for (; i < 2 * B; i += blockDim.x) {
        mnmx[2 * i + 0] = 0x7F800000u;  // +inf
        mnmx[2 * i + 1] = 0u;           // 0.0f (mag >= 0)
    }
}

// ---------------- K1: grayscale + uint8 quantize (both sources) ----------------
__global__ void k_gray(const float* __restrict__ vis, const float* __restrict__ ir,
                       uint8_t* __restrict__ qvis, uint8_t* __restrict__ qir, int B) {
    int tid = blockIdx.x * blockDim.x + threadIdx.x;
    int n4 = B * (HW / 4);
    const float* img;
    uint8_t* q;
    if (tid < n4) {
        img = vis; q = qvis;
    } else {
        tid -= n4;
        if (tid >= n4) return;
        img = ir; q = qir;
    }
    int b  = tid / (HW / 4);
    int i4 = tid % (HW / 4);
    const float4* p4 = (const float4*)(img + (size_t)b * 3 * HW);
    float4 r  = p4[i4];
    float4 g  = p4[i4 + (HW / 4)];
    float4 bl = p4[i4 + 2 * (HW / 4)];
    uchar4 o;
    o.x = (uint8_t)((0.2989f * r.x + 0.587f * g.x + 0.114f * bl.x) * 255.0f);
    o.y = (uint8_t)((0.2989f * r.y + 0.587f * g.y + 0.114f * bl.y) * 255.0f);
    o.z = (uint8_t)((0.2989f * r.z + 0.587f * g.z + 0.114f * bl.z) * 255.0f);
    o.w = (uint8_t)((0.2989f * r.w + 0.587f * g.w + 0.114f * bl.w) * 255.0f);
    *(uchar4*)(q + (size_t)b * HW + (size_t)i4 * 4) = o;
}

// ---------------- K2: per-image min/max of sobel magnitude ----------------
// wave-per-row; block = 4 waves = 4 consecutive rows of one (src, b)
__global__ void k_minmax(const uint8_t* __restrict__ qvis, const uint8_t* __restrict__ qir,
                         uint32_t* __restrict__ mnmx, int B) {
    int wid = threadIdx.x >> 6, lane = threadIdx.x & 63;
    int task = blockIdx.x;                 // [0, 2*B*H/4)
    int src = task / (B * (H / 4));
    int rem = task % (B * (H / 4));
    int b = rem / (H / 4);
    int y = (rem % (H / 4)) * 4 + wid;
    const uint8_t* q = (src ? qir : qvis) + (size_t)b * HW;

    float mag[8];
    sobel_row8(q, y, lane, mag);
    float mn = mag[0], mx = mag[0];
    #pragma unroll
    for (int k = 1; k < 8; ++k) { mn = fminf(mn, mag[k]); mx = fmaxf(mx, mag[k]); }
    #pragma unroll
    for (int o = 32; o > 0; o >>= 1) {
        mn = fminf(mn, __shfl_down(mn, o));
        mx = fmaxf(mx, __shfl_down(mx, o));
    }
    __shared__ float smn[4], smx[4];
    if (lane == 0) { smn[wid] = mn; smx[wid] = mx; }
    __syncthreads();
    if (threadIdx.x == 0) {
        #pragma unroll
        for (int w = 1; w < 4; ++w) { mn = fminf(mn, smn[w]); mx = fmaxf(mx, smx[w]); }
        atomicMin(&mnmx[(src * B + b) * 2 + 0], __float_as_uint(mn));
        atomicMax(&mnmx[(src * B + b) * 2 + 1], __float_as_uint(mx));
    }
}

// ---------------- K3: weighted blend + |diff| partial sums ----------------
// wave-per-row; block = 4 waves = 4 consecutive rows of image b
__global__ void k_loss(const float* __restrict__ vis, const float* __restrict__ ir,
                       const float* __restrict__ fus,
                       const uint8_t* __restrict__ qvis, const uint8_t* __restrict__ qir,
                       const uint32_t* __restrict__ mnmx,
                       float* __restrict__ partial, int B) {
    int wid = threadIdx.x >> 6, lane = threadIdx.x & 63;
    int task = blockIdx.x;                 // [0, B*H/4)
    int b = task / (H / 4);
    int y = (task % (H / 4)) * 4 + wid;

    float mn_v = __uint_as_float(mnmx[(0 * B + b) * 2 + 0]);
    float mx_v = __uint_as_float(mnmx[(0 * B + b) * 2 + 1]);
    float mn_i = __uint_as_float(mnmx[(1 * B + b) * 2 + 0]);
    float mx_i = __uint_as_float(mnmx[(1 * B + b) * 2 + 1]);
    float inv_v = 1.0f / fmaxf(mx_v - mn_v, 1e-8f);
    float inv_i = 1.0f / fmaxf(mx_i - mn_i, 1e-8f);

    float mv[8], mi[8];
    sobel_row8(qvis + (size_t)b * HW, y, lane, mv);
    sobel_row8(qir  + (size_t)b * HW, y, lane, mi);

    float wv[8], wi[8];
    #pragma unroll
    for (int k = 0; k < 8; ++k) {
        float sv = (mv[k] - mn_v) * inv_v;
        float si = (mi[k] - mn_i) * inv_i;
        float den = sv + si + 1e-8f;
        float rden = 1.0f / den;
        wv[k] = sv * rden;
        wi[k] = si * rden;
    }

    float acc = 0.0f;
    int i = y * W + lane * 8;  // pixel index within image
    #pragma unroll
    for (int ch = 0; ch < 3; ++ch) {
        size_t e4 = ((((size_t)b * 3 + ch) * HW) + i) >> 2;
        const float4* v4 = (const float4*)vis;
        const float4* r4 = (const float4*)ir;
        const float4* f4 = (const float4*)fus;
        float4 va = v4[e4],     vb = v4[e4 + 1];
        float4 ra = r4[e4],     rb = r4[e4 + 1];
        float4 fa = f4[e4],     fb = f4[e4 + 1];
        acc += fabsf(wv[0] * va.x + wi[0] * ra.x - fa.x);
        acc += fabsf(wv[1] * va.y + wi[1] * ra.y - fa.y);
        acc += fabsf(wv[2] * va.z + wi[2] * ra.z - fa.z);
        acc += fabsf(wv[3] * va.w + wi[3] * ra.w - fa.w);
        acc += fabsf(wv[4] * vb.x + wi[4] * rb.x - fb.x);
        acc += fabsf(wv[5] * vb.y + wi[5] * rb.y - fb.y);
        acc += fabsf(wv[6] * vb.z + wi[6] * rb.z - fb.z);
        acc += fabsf(wv[7] * vb.w + wi[7] * rb.w - fb.w);
    }

    #pragma unroll
    for (int o = 32; o > 0; o >>= 1) acc += __shfl_down(acc, o);
    __shared__ float ssum[4];
    if (lane == 0) ssum[wid] = acc;
    __syncthreads();
    if (threadIdx.x == 0) {
        partial[blockIdx.x] = ssum[0] + ssum[1] + ssum[2] + ssum[3];
    }
}

// ---------------- K4: final reduce ----------------
__global__ void k_final(const float* __restrict__ partial, int n, float* __restrict__ out,
                        long long N) {
    double s = 0.0;
    for (int i = threadIdx.x; i < n; i += 256) s += (double)partial[i];
    __shared__ double sm[256];
    sm[threadIdx.x] = s;
    __syncthreads();
    for (int k = 128; k > 0; k >>= 1) {
        if (threadIdx.x < k) sm[threadIdx.x] += sm[threadIdx.x + k];
        __syncthreads();
    }
    if (threadIdx.x == 0) out[0] = (float)(sm[0] / (double)N);
}

extern "C" void kernel_launch(void* const* d_in, const int* in_sizes, int n_in,
                              void* d_out, int out_size, void* d_ws, size_t ws_size,
                              hipStream_t stream) {
    const float* vis = (const float*)d_in[0];
    const float* ir  = (const float*)d_in[1];
    const float* fus = (const float*)d_in[2];
    int B = in_sizes[0] / (3 * HW);  // 16

    uint8_t* qvis = (uint8_t*)d_ws;
    uint8_t* qir  = qvis + (size_t)B * HW;
    uint32_t* mnmx = (uint32_t*)(qir + (size_t)B * HW);
    float* partial = (float*)(mnmx + 4 * B);
    float* out = (float*)d_out;

    k_init<<<1, 64, 0, stream>>>(mnmx, B);

    int n1 = 2 * B * (HW / 4);
    k_gray<<<(n1 + 255) / 256, 256, 0, stream>>>(vis, ir, qvis, qir, B);

    int nblk_mm = 2 * B * (H / 4);   // 4096 blocks, wave-per-row
    k_minmax<<<nblk_mm, 256, 0, stream>>>(qvis, qir, mnmx, B);

    int nblk_loss = B * (H / 4);     // 2048 blocks, wave-per-row
    k_loss<<<nblk_loss, 256, 0, stream>>>(vis, ir, fus, qvis, qir, mnmx, partial, B);

    k_final<<<1, 256, 0, stream>>>(partial, nblk_loss, out, (long long)B * 3 * HW);
}

// Round 3
// 75.818 us; speedup vs baseline: 1.7238x; 1.5523x over previous
//
#include <hip/hip_runtime.h>
#include <hip/hip_bf16.h>
#include <stdint.h>

#define H 512
#define W 512
#define HW (H * W)
#define TR 8            // core rows per k_sal block
#define NSLOT (TR + 2)  // core + 2 halo rows
#define LSTR 520        // 4 pad + 512 + 4 pad bytes per LDS row

__device__ __forceinline__ int refl(int i, int n) {
    // BORDER_REFLECT_101: -1 -> 1, n -> n-2
    return i < 0 ? -i : (i >= n ? 2 * n - 2 - i : i);
}

// 10 stencil columns (x0-1 .. x0+8) from a 16-byte window starting at x0-4.
__device__ __forceinline__ void cols10(uint2 lo, uint2 hi, float* __restrict__ c) {
    c[0] = (float)(lo.x >> 24);
    c[1] = (float)(lo.y & 0xffu);
    c[2] = (float)((lo.y >> 8) & 0xffu);
    c[3] = (float)((lo.y >> 16) & 0xffu);
    c[4] = (float)(lo.y >> 24);
    c[5] = (float)(hi.x & 0xffu);
    c[6] = (float)((hi.x >> 8) & 0xffu);
    c[7] = (float)((hi.x >> 16) & 0xffu);
    c[8] = (float)(hi.x >> 24);
    c[9] = (float)(hi.y & 0xffu);
}

// ---------------- K1: fused gray + sobel + per-image min/max + q emit ----------------
// block = 256 threads, owns 8 rows of one image b, BOTH sources.
__global__ __launch_bounds__(256) void k_sal(const float* __restrict__ vis,
                                             const float* __restrict__ ir,
                                             uint8_t* __restrict__ qvis,
                                             uint8_t* __restrict__ qir,
                                             uint32_t* __restrict__ mnmx, int B) {
    __shared__ uint8_t g[2][NSLOT][LSTR];
    __shared__ float red[4][4];
    int tid = threadIdx.x;
    int b  = blockIdx.x >> 6;            // H/TR = 64 strips per image
    int y0 = (blockIdx.x & 63) * TR;

    // Phase 1: grayscale rows y0-1 .. y0+TR (reflected) into LDS, both sources.
    // tasks: 2 src x 10 slots x 128 float4-segs = 2560; 10 per thread.
    for (int it = 0; it < 10; ++it) {
        int idx = tid + it * 256;
        int src = idx >= 1280;
        int rem = src ? idx - 1280 : idx;
        int j   = rem >> 7;
        int seg = rem & 127;
        int row = refl(y0 - 1 + j, H);
        const float4* p4 = (const float4*)((src ? ir : vis) + (size_t)b * 3 * HW);
        int o = row * (W / 4) + seg;
        float4 r  = p4[o];
        float4 gg = p4[o + HW / 4];
        float4 bb = p4[o + 2 * (HW / 4)];
        uchar4 q;
        q.x = (uint8_t)((0.2989f * r.x + 0.587f * gg.x + 0.114f * bb.x) * 255.0f);
        q.y = (uint8_t)((0.2989f * r.y + 0.587f * gg.y + 0.114f * bb.y) * 255.0f);
        q.z = (uint8_t)((0.2989f * r.z + 0.587f * gg.z + 0.114f * bb.z) * 255.0f);
        q.w = (uint8_t)((0.2989f * r.w + 0.587f * gg.w + 0.114f * bb.w) * 255.0f);
        *(uchar4*)&g[src][j][4 + seg * 4] = q;
    }
    __syncthreads();
    // reflect-101 column pads: byte 3 is x=-1 -> gray[1]; byte 516 is x=512 -> gray[510]
    if (tid < 2 * NSLOT) {
        int src = tid >= NSLOT;
        int j = src ? tid - NSLOT : tid;
        g[src][j][3]       = g[src][j][4 + 1];
        g[src][j][4 + 512] = g[src][j][4 + 510];
    }
    __syncthreads();

    // Phase 2: sobel on core rows from LDS + q writeback + min/max.
    // tasks: 2 src x 8 rows x 64 segs = 1024; 4 per thread.
    float mn0 = INFINITY, mx0 = 0.0f, mn1 = INFINITY, mx1 = 0.0f;
    #pragma unroll
    for (int k = 0; k < 4; ++k) {
        int task = tid + k * 256;
        int src = k >> 1;                 // tasks 0..511 src0, 512..1023 src1
        int r   = (task >> 6) & (TR - 1); // core row index 0..7 -> slot r+1
        int s8  = task & 63;              // 8-px segment
        const uint8_t* rp0 = &g[src][r][s8 * 8];
        const uint8_t* rp1 = &g[src][r + 1][s8 * 8];
        const uint8_t* rp2 = &g[src][r + 2][s8 * 8];
        uint2 a0 = *(const uint2*)rp0, b0 = *(const uint2*)(rp0 + 8);
        uint2 a1 = *(const uint2*)rp1, b1 = *(const uint2*)(rp1 + 8);
        uint2 a2 = *(const uint2*)rp2, b2 = *(const uint2*)(rp2 + 8);
        // q writeback: image row y0+r bytes s8*8..+7 = window bytes 4..11 of center row
        uint2 qw; qw.x = a1.y; qw.y = b1.x;
        uint8_t* qp = (src ? qir : qvis) + (size_t)b * HW + (size_t)(y0 + r) * W + s8 * 8;
        *(uint2*)qp = qw;
        float c0[10], c1[10], c2[10];
        cols10(a0, b0, c0);
        cols10(a1, b1, c1);
        cols10(a2, b2, c2);
        float sx[10], sy[10];
        #pragma unroll
        for (int j = 0; j < 10; ++j) {
            sx[j] = c0[j] + 2.0f * c1[j] + c2[j];
            sy[j] = c2[j] - c0[j];
        }
        float lmn = INFINITY, lmx = 0.0f;
        #pragma unroll
        for (int p = 0; p < 8; ++p) {
            float gx = sx[p + 2] - sx[p];
            float gy = sy[p] + 2.0f * sy[p + 1] + sy[p + 2];
            float m = sqrtf(gx * gx + gy * gy);
            lmn = fminf(lmn, m);
            lmx = fmaxf(lmx, m);
        }
        if (src == 0) { mn0 = fminf(mn0, lmn); mx0 = fmaxf(mx0, lmx); }
        else          { mn1 = fminf(mn1, lmn); mx1 = fmaxf(mx1, lmx); }
    }

    // wave reduce all four
    #pragma unroll
    for (int o = 32; o > 0; o >>= 1) {
        mn0 = fminf(mn0, __shfl_down(mn0, o));
        mx0 = fmaxf(mx0, __shfl_down(mx0, o));
        mn1 = fminf(mn1, __shfl_down(mn1, o));
        mx1 = fmaxf(mx1, __shfl_down(mx1, o));
    }
    int lane = tid & 63, w = tid >> 6;
    if (lane == 0) { red[w][0] = mn0; red[w][1] = mx0; red[w][2] = mn1; red[w][3] = mx1; }
    __syncthreads();
    if (tid == 0) {
        #pragma unroll
        for (int ww = 1; ww < 4; ++ww) {
            mn0 = fminf(mn0, red[ww][0]); mx0 = fmaxf(mx0, red[ww][1]);
            mn1 = fminf(mn1, red[ww][2]); mx1 = fmaxf(mx1, red[ww][3]);
        }
        // slots memset to 0xFFFFFFFF; max stored complemented so atomicMin works for both
        atomicMin(&mnmx[(0 * B + b) * 2 + 0], __float_as_uint(mn0));
        atomicMin(&mnmx[(0 * B + b) * 2 + 1], ~__float_as_uint(mx0));
        atomicMin(&mnmx[(1 * B + b) * 2 + 0], __float_as_uint(mn1));
        atomicMin(&mnmx[(1 * B + b) * 2 + 1], ~__float_as_uint(mx1));
    }
}

// Extract this lane's 10 stencil columns from an 8-byte row segment via shuffles.
__device__ __forceinline__ void row_cols(uint2 v, int lane, float* __restrict__ c) {
    uint32_t lx = __shfl_up(v.y, 1);
    uint32_t rx = __shfl_down(v.x, 1);
    uint32_t lb = (lane == 0)  ? ((v.x >> 8) & 0xffu)  : (lx >> 24);
    uint32_t rb = (lane == 63) ? ((v.y >> 16) & 0xffu) : (rx & 0xffu);
    c[0] = (float)lb;
    c[1] = (float)(v.x & 0xffu);
    c[2] = (float)((v.x >> 8) & 0xffu);
    c[3] = (float)((v.x >> 16) & 0xffu);
    c[4] = (float)(v.x >> 24);
    c[5] = (float)(v.y & 0xffu);
    c[6] = (float)((v.y >> 8) & 0xffu);
    c[7] = (float)((v.y >> 16) & 0xffu);
    c[8] = (float)(v.y >> 24);
    c[9] = (float)rb;
}

__device__ __forceinline__ void sobel_row8(const uint8_t* __restrict__ q, int y, int lane,
                                           float* __restrict__ mag) {
    const uint2* rm = (const uint2*)(q + (size_t)refl(y - 1, H) * W);
    const uint2* r0 = (const uint2*)(q + (size_t)y * W);
    const uint2* rp = (const uint2*)(q + (size_t)refl(y + 1, H) * W);
    uint2 vm = rm[lane], v0 = r0[lane], vp = rp[lane];
    float c0[10], c1[10], c2[10];
    row_cols(vm, lane, c0);
    row_cols(v0, lane, c1);
    row_cols(vp, lane, c2);
    float sx[10], sy[10];
    #pragma unroll
    for (int j = 0; j < 10; ++j) {
        sx[j] = c0[j] + 2.0f * c1[j] + c2[j];
        sy[j] = c2[j] - c0[j];
    }
    #pragma unroll
    for (int k = 0; k < 8; ++k) {
        float gx = sx[k + 2] - sx[k];
        float gy = sy[k] + 2.0f * sy[k + 1] + sy[k + 2];
        mag[k] = sqrtf(gx * gx + gy * gy);
    }
}

// ---------------- K2: weighted blend + |diff| partial sums ----------------
// block = 4 waves; each wave handles rows y0+w and y0+w+4 (8 rows per block)
__global__ __launch_bounds__(256) void k_loss(const float* __restrict__ vis,
                                              const float* __restrict__ ir,
                                              const float* __restrict__ fus,
                                              const uint8_t* __restrict__ qvis,
                                              const uint8_t* __restrict__ qir,
                                              const uint32_t* __restrict__ mnmx,
                                              float* __restrict__ partial, int B) {
    int w = threadIdx.x >> 6, lane = threadIdx.x & 63;
    int b = blockIdx.x >> 6;
    int y0 = (blockIdx.x & 63) * 8;

    float mn_v = __uint_as_float(mnmx[(0 * B + b) * 2 + 0]);
    float mx_v = __uint_as_float(~mnmx[(0 * B + b) * 2 + 1]);
    float mn_i = __uint_as_float(mnmx[(1 * B + b) * 2 + 0]);
    float mx_i = __uint_as_float(~mnmx[(1 * B + b) * 2 + 1]);
    float inv_v = 1.0f / fmaxf(mx_v - mn_v, 1e-8f);
    float inv_i = 1.0f / fmaxf(mx_i - mn_i, 1e-8f);

    float acc = 0.0f;
    #pragma unroll
    for (int rr = 0; rr < 2; ++rr) {
        int y = y0 + w + rr * 4;
        float mv[8], mi[8];
        sobel_row8(qvis + (size_t)b * HW, y, lane, mv);
        sobel_row8(qir  + (size_t)b * HW, y, lane, mi);

        float wv[8], wi[8];
        #pragma unroll
        for (int k = 0; k < 8; ++k) {
            float sv = (mv[k] - mn_v) * inv_v;
            float si = (mi[k] - mn_i) * inv_i;
            float den = sv + si + 1e-8f;
            float rden = 1.0f / den;
            wv[k] = sv * rden;
            wi[k] = si * rden;
        }

        int i = y * W + lane * 8;
        #pragma unroll
        for (int ch = 0; ch < 3; ++ch) {
            size_t e4 = ((((size_t)b * 3 + ch) * HW) + i) >> 2;
            const float4* v4 = (const float4*)vis;
            const float4* r4 = (const float4*)ir;
            const float4* f4 = (const float4*)fus;
            float4 va = v4[e4], vb = v4[e4 + 1];
            float4 ra = r4[e4], rb = r4[e4 + 1];
            float4 fa = f4[e4], fb = f4[e4 + 1];
            acc += fabsf(wv[0] * va.x + wi[0] * ra.x - fa.x);
            acc += fabsf(wv[1] * va.y + wi[1] * ra.y - fa.y);
            acc += fabsf(wv[2] * va.z + wi[2] * ra.z - fa.z);
            acc += fabsf(wv[3] * va.w + wi[3] * ra.w - fa.w);
            acc += fabsf(wv[4] * vb.x + wi[4] * rb.x - fb.x);
            acc += fabsf(wv[5] * vb.y + wi[5] * rb.y - fb.y);
            acc += fabsf(wv[6] * vb.z + wi[6] * rb.z - fb.z);
            acc += fabsf(wv[7] * vb.w + wi[7] * rb.w - fb.w);
        }
    }

    #pragma unroll
    for (int o = 32; o > 0; o >>= 1) acc += __shfl_down(acc, o);
    __shared__ float ssum[4];
    if (lane == 0) ssum[w] = acc;
    __syncthreads();
    if (threadIdx.x == 0) partial[blockIdx.x] = ssum[0] + ssum[1] + ssum[2] + ssum[3];
}

// ---------------- K3: final reduce ----------------
__global__ void k_final(const float* __restrict__ partial, int n, float* __restrict__ out,
                        long long N) {
    double s = 0.0;
    for (int i = threadIdx.x; i < n; i += 256) s += (double)partial[i];
    __shared__ double sm[256];
    sm[threadIdx.x] = s;
    __syncthreads();
    for (int k = 128; k > 0; k >>= 1) {
        if (threadIdx.x < k) sm[threadIdx.x] += sm[threadIdx.x + k];
        __syncthreads();
    }
    if (threadIdx.x == 0) out[0] = (float)(sm[0] / (double)N);
}

extern "C" void kernel_launch(void* const* d_in, const int* in_sizes, int n_in,
                              void* d_out, int out_size, void* d_ws, size_t ws_size,
                              hipStream_t stream) {
    const float* vis = (const float*)d_in[0];
    const float* ir  = (const float*)d_in[1];
    const float* fus = (const float*)d_in[2];
    int B = in_sizes[0] / (3 * HW);  // 16

    uint8_t* qvis = (uint8_t*)d_ws;
    uint8_t* qir  = qvis + (size_t)B * HW;
    uint32_t* mnmx = (uint32_t*)(qir + (size_t)B * HW);
    float* partial = (float*)(mnmx + 4 * B);
    float* out = (float*)d_out;

    // all-ones init: min slots use atomicMin(bits), max slots atomicMin(~bits)
    hipMemsetAsync(mnmx, 0xFF, (size_t)4 * B * sizeof(uint32_t), stream);

    int nblk_sal = B * (H / TR);     // 1024 blocks
    k_sal<<<nblk_sal, 256, 0, stream>>>(vis, ir, qvis, qir, mnmx, B);

    int nblk_loss = B * (H / 8);     // 1024 blocks
    k_loss<<<nblk_loss, 256, 0, stream>>>(vis, ir, fus, qvis, qir, mnmx, partial, B);

    k_final<<<1, 256, 0, stream>>>(partial, nblk_loss, out, (long long)B * 3 * HW);
}

// Round 4
// 73.858 us; speedup vs baseline: 1.7696x; 1.0265x over previous
//
#include <hip/hip_runtime.h>
#include <hip/hip_bf16.h>
#include <stdint.h>

#define H 512
#define W 512
#define HW (H * W)
#define TR 8            // core rows per k_sal block
#define NSLOT (TR + 2)  // core + 2 halo rows
#define LSTR 520        // 4 pad + 512 + 4 pad bytes per LDS row

__device__ __forceinline__ int refl(int i, int n) {
    // BORDER_REFLECT_101: -1 -> 1, n -> n-2
    return i < 0 ? -i : (i >= n ? 2 * n - 2 - i : i);
}

// 10 stencil columns (x0-1 .. x0+8) from a 16-byte window starting at x0-4.
__device__ __forceinline__ void cols10(uint2 lo, uint2 hi, float* __restrict__ c) {
    c[0] = (float)(lo.x >> 24);
    c[1] = (float)(lo.y & 0xffu);
    c[2] = (float)((lo.y >> 8) & 0xffu);
    c[3] = (float)((lo.y >> 16) & 0xffu);
    c[4] = (float)(lo.y >> 24);
    c[5] = (float)(hi.x & 0xffu);
    c[6] = (float)((hi.x >> 8) & 0xffu);
    c[7] = (float)((hi.x >> 16) & 0xffu);
    c[8] = (float)(hi.x >> 24);
    c[9] = (float)(hi.y & 0xffu);
}

// ---------------- K1: fused gray + sobel + per-image min/max + q emit ----------------
// block = 256 threads, owns 8 rows of ONE source of one image.
__global__ __launch_bounds__(256) void k_sal(const float* __restrict__ vis,
                                             const float* __restrict__ ir,
                                             uint8_t* __restrict__ qvis,
                                             uint8_t* __restrict__ qir,
                                             uint32_t* __restrict__ mnmx, int B) {
    __shared__ uint8_t g[NSLOT][LSTR];
    __shared__ float red[4][2];
    int tid = threadIdx.x;
    int per_src = B * (H / TR);          // 1024
    int blk = blockIdx.x;
    int src = blk >= per_src;
    int rem = src ? blk - per_src : blk;
    int b  = rem >> 6;                   // H/TR = 64 strips per image
    int y0 = (rem & 63) * TR;

    const float4* p4 = (const float4*)((src ? ir : vis) + (size_t)b * 3 * HW);
    uint8_t* q = (src ? qir : qvis) + (size_t)b * HW;

    // Phase 1a: issue ALL 15 loads (5 tasks x 3 channels) before any use.
    // tasks: 10 slots x 128 float4-segs = 1280; 5 per thread.
    float4 R[5], G[5], Bl[5];
    #pragma unroll
    for (int it = 0; it < 5; ++it) {
        int t = tid + it * 256;
        int j = t >> 7, seg = t & 127;
        int row = refl(y0 - 1 + j, H);
        int o = row * (W / 4) + seg;
        R[it]  = p4[o];
        G[it]  = p4[o + HW / 4];
        Bl[it] = p4[o + 2 * (HW / 4)];
    }
    // Phase 1b: gray + quantize + LDS write.
    #pragma unroll
    for (int it = 0; it < 5; ++it) {
        int t = tid + it * 256;
        int j = t >> 7, seg = t & 127;
        uchar4 qq;
        qq.x = (uint8_t)((0.2989f * R[it].x + 0.587f * G[it].x + 0.114f * Bl[it].x) * 255.0f);
        qq.y = (uint8_t)((0.2989f * R[it].y + 0.587f * G[it].y + 0.114f * Bl[it].y) * 255.0f);
        qq.z = (uint8_t)((0.2989f * R[it].z + 0.587f * G[it].z + 0.114f * Bl[it].z) * 255.0f);
        qq.w = (uint8_t)((0.2989f * R[it].w + 0.587f * G[it].w + 0.114f * Bl[it].w) * 255.0f);
        *(uchar4*)&g[j][4 + seg * 4] = qq;
    }
    __syncthreads();
    // reflect-101 column pads: byte 3 is x=-1 -> gray[1]; byte 516 is x=512 -> gray[510]
    if (tid < NSLOT) {
        g[tid][3]   = g[tid][5];    // 4+1
        g[tid][516] = g[tid][514];  // 4+510
    }
    __syncthreads();

    // Phase 2: sobel on core rows from LDS + q writeback + min/max.
    // tasks: 8 rows x 64 segs = 512; 2 per thread.
    float mn = INFINITY, mx = 0.0f;
    #pragma unroll
    for (int k = 0; k < 2; ++k) {
        int task = tid + k * 256;
        int r  = task >> 6;   // 0..7 -> slots r, r+1, r+2
        int s8 = task & 63;   // 8-px segment
        const uint8_t* rp0 = &g[r][s8 * 8];
        const uint8_t* rp1 = &g[r + 1][s8 * 8];
        const uint8_t* rp2 = &g[r + 2][s8 * 8];
        uint2 a0 = *(const uint2*)rp0, b0 = *(const uint2*)(rp0 + 8);
        uint2 a1 = *(const uint2*)rp1, b1 = *(const uint2*)(rp1 + 8);
        uint2 a2 = *(const uint2*)rp2, b2 = *(const uint2*)(rp2 + 8);
        // q writeback: image row y0+r bytes s8*8..+7 = window bytes 4..11 of center row
        uint2 qw; qw.x = a1.y; qw.y = b1.x;
        *(uint2*)(q + (size_t)(y0 + r) * W + s8 * 8) = qw;
        float c0[10], c1[10], c2[10];
        cols10(a0, b0, c0);
        cols10(a1, b1, c1);
        cols10(a2, b2, c2);
        float sx[10], sy[10];
        #pragma unroll
        for (int j = 0; j < 10; ++j) {
            sx[j] = c0[j] + 2.0f * c1[j] + c2[j];
            sy[j] = c2[j] - c0[j];
        }
        #pragma unroll
        for (int p = 0; p < 8; ++p) {
            float gx = sx[p + 2] - sx[p];
            float gy = sy[p] + 2.0f * sy[p + 1] + sy[p + 2];
            float m = sqrtf(gx * gx + gy * gy);
            mn = fminf(mn, m);
            mx = fmaxf(mx, m);
        }
    }

    // block reduce + atomics
    #pragma unroll
    for (int o = 32; o > 0; o >>= 1) {
        mn = fminf(mn, __shfl_down(mn, o));
        mx = fmaxf(mx, __shfl_down(mx, o));
    }
    int lane = tid & 63, w = tid >> 6;
    if (lane == 0) { red[w][0] = mn; red[w][1] = mx; }
    __syncthreads();
    if (tid == 0) {
        #pragma unroll
        for (int ww = 1; ww < 4; ++ww) {
            mn = fminf(mn, red[ww][0]);
            mx = fmaxf(mx, red[ww][1]);
        }
        // slots memset to 0xFFFFFFFF; max stored complemented so atomicMin works for both
        atomicMin(&mnmx[(src * B + b) * 2 + 0], __float_as_uint(mn));
        atomicMin(&mnmx[(src * B + b) * 2 + 1], ~__float_as_uint(mx));
    }
}

// Extract this lane's 10 stencil columns from an 8-byte row segment via shuffles.
__device__ __forceinline__ void row_cols(uint2 v, int lane, float* __restrict__ c) {
    uint32_t lx = __shfl_up(v.y, 1);
    uint32_t rx = __shfl_down(v.x, 1);
    uint32_t lb = (lane == 0)  ? ((v.x >> 8) & 0xffu)  : (lx >> 24);
    uint32_t rb = (lane == 63) ? ((v.y >> 16) & 0xffu) : (rx & 0xffu);
    c[0] = (float)lb;
    c[1] = (float)(v.x & 0xffu);
    c[2] = (float)((v.x >> 8) & 0xffu);
    c[3] = (float)((v.x >> 16) & 0xffu);
    c[4] = (float)(v.x >> 24);
    c[5] = (float)(v.y & 0xffu);
    c[6] = (float)((v.y >> 8) & 0xffu);
    c[7] = (float)((v.y >> 16) & 0xffu);
    c[8] = (float)(v.y >> 24);
    c[9] = (float)rb;
}

__device__ __forceinline__ void sobel_row8(const uint8_t* __restrict__ q, int y, int lane,
                                           float* __restrict__ mag) {
    const uint2* rm = (const uint2*)(q + (size_t)refl(y - 1, H) * W);
    const uint2* r0 = (const uint2*)(q + (size_t)y * W);
    const uint2* rp = (const uint2*)(q + (size_t)refl(y + 1, H) * W);
    uint2 vm = rm[lane], v0 = r0[lane], vp = rp[lane];
    float c0[10], c1[10], c2[10];
    row_cols(vm, lane, c0);
    row_cols(v0, lane, c1);
    row_cols(vp, lane, c2);
    float sx[10], sy[10];
    #pragma unroll
    for (int j = 0; j < 10; ++j) {
        sx[j] = c0[j] + 2.0f * c1[j] + c2[j];
        sy[j] = c2[j] - c0[j];
    }
    #pragma unroll
    for (int k = 0; k < 8; ++k) {
        float gx = sx[k + 2] - sx[k];
        float gy = sy[k] + 2.0f * sy[k + 1] + sy[k + 2];
        mag[k] = sqrtf(gx * gx + gy * gy);
    }
}

// ---------------- K2: weighted blend + |diff| partial sums ----------------
// block = 4 waves; each wave handles rows y0+w and y0+w+4 (8 rows per block)
__global__ __launch_bounds__(256) void k_loss(const float* __restrict__ vis,
                                              const float* __restrict__ ir,
                                              const float* __restrict__ fus,
                                              const uint8_t* __restrict__ qvis,
                                              const uint8_t* __restrict__ qir,
                                              const uint32_t* __restrict__ mnmx,
                                              float* __restrict__ partial, int B) {
    int w = threadIdx.x >> 6, lane = threadIdx.x & 63;
    int b = blockIdx.x >> 6;
    int y0 = (blockIdx.x & 63) * 8;

    float mn_v = __uint_as_float(mnmx[(0 * B + b) * 2 + 0]);
    float mx_v = __uint_as_float(~mnmx[(0 * B + b) * 2 + 1]);
    float mn_i = __uint_as_float(mnmx[(1 * B + b) * 2 + 0]);
    float mx_i = __uint_as_float(~mnmx[(1 * B + b) * 2 + 1]);
    float inv_v = 1.0f / fmaxf(mx_v - mn_v, 1e-8f);
    float inv_i = 1.0f / fmaxf(mx_i - mn_i, 1e-8f);

    float acc = 0.0f;
    #pragma unroll
    for (int rr = 0; rr < 2; ++rr) {
        int y = y0 + w + rr * 4;
        float mv[8], mi[8];
        sobel_row8(qvis + (size_t)b * HW, y, lane, mv);
        sobel_row8(qir  + (size_t)b * HW, y, lane, mi);

        float wv[8], wi[8];
        #pragma unroll
        for (int k = 0; k < 8; ++k) {
            float sv = (mv[k] - mn_v) * inv_v;
            float si = (mi[k] - mn_i) * inv_i;
            float den = sv + si + 1e-8f;
            float rden = 1.0f / den;
            wv[k] = sv * rden;
            wi[k] = si * rden;
        }

        int i = y * W + lane * 8;
        #pragma unroll
        for (int ch = 0; ch < 3; ++ch) {
            size_t e4 = ((((size_t)b * 3 + ch) * HW) + i) >> 2;
            const float4* v4 = (const float4*)vis;
            const float4* r4 = (const float4*)ir;
            const float4* f4 = (const float4*)fus;
            float4 va = v4[e4], vb = v4[e4 + 1];
            float4 ra = r4[e4], rb = r4[e4 + 1];
            float4 fa = f4[e4], fb = f4[e4 + 1];
            acc += fabsf(wv[0] * va.x + wi[0] * ra.x - fa.x);
            acc += fabsf(wv[1] * va.y + wi[1] * ra.y - fa.y);
            acc += fabsf(wv[2] * va.z + wi[2] * ra.z - fa.z);
            acc += fabsf(wv[3] * va.w + wi[3] * ra.w - fa.w);
            acc += fabsf(wv[4] * vb.x + wi[4] * rb.x - fb.x);
            acc += fabsf(wv[5] * vb.y + wi[5] * rb.y - fb.y);
            acc += fabsf(wv[6] * vb.z + wi[6] * rb.z - fb.z);
            acc += fabsf(wv[7] * vb.w + wi[7] * rb.w - fb.w);
        }
    }

    #pragma unroll
    for (int o = 32; o > 0; o >>= 1) acc += __shfl_down(acc, o);
    __shared__ float ssum[4];
    if (lane == 0) ssum[w] = acc;
    __syncthreads();
    if (threadIdx.x == 0) partial[blockIdx.x] = ssum[0] + ssum[1] + ssum[2] + ssum[3];
}

// ---------------- K3: final reduce ----------------
__global__ void k_final(const float* __restrict__ partial, int n, float* __restrict__ out,
                        long long N) {
    double s = 0.0;
    for (int i = threadIdx.x; i < n; i += 256) s += (double)partial[i];
    __shared__ double sm[256];
    sm[threadIdx.x] = s;
    __syncthreads();
    for (int k = 128; k > 0; k >>= 1) {
        if (threadIdx.x < k) sm[threadIdx.x] += sm[threadIdx.x + k];
        __syncthreads();
    }
    if (threadIdx.x == 0) out[0] = (float)(sm[0] / (double)N);
}

extern "C" void kernel_launch(void* const* d_in, const int* in_sizes, int n_in,
                              void* d_out, int out_size, void* d_ws, size_t ws_size,
                              hipStream_t stream) {
    const float* vis = (const float*)d_in[0];
    const float* ir  = (const float*)d_in[1];
    const float* fus = (const float*)d_in[2];
    int B = in_sizes[0] / (3 * HW);  // 16

    uint8_t* qvis = (uint8_t*)d_ws;
    uint8_t* qir  = qvis + (size_t)B * HW;
    uint32_t* mnmx = (uint32_t*)(qir + (size_t)B * HW);
    float* partial = (float*)(mnmx + 4 * B);
    float* out = (float*)d_out;

    // all-ones init: min slots use atomicMin(bits), max slots atomicMin(~bits)
    hipMemsetAsync(mnmx, 0xFF, (size_t)4 * B * sizeof(uint32_t), stream);

    int nblk_sal = 2 * B * (H / TR); // 2048 blocks, one source each
    k_sal<<<nblk_sal, 256, 0, stream>>>(vis, ir, qvis, qir, mnmx, B);

    int nblk_loss = B * (H / 8);     // 1024 blocks
    k_loss<<<nblk_loss, 256, 0, stream>>>(vis, ir, fus, qvis, qir, mnmx, partial, B);

    k_final<<<1, 256, 0, stream>>>(partial, nblk_loss, out, (long long)B * 3 * HW);
}

// Round 5
// 72.739 us; speedup vs baseline: 1.7968x; 1.0154x over previous
//
#include <hip/hip_runtime.h>
#include <hip/hip_bf16.h>
#include <stdint.h>

#define H 512
#define W 512
#define HW (H * W)
#define TR 8            // core rows per k_sal block
#define NSLOT (TR + 2)  // core + 2 halo rows
#define LSTR 520        // 4 pad + 512 + 4 pad bytes per LDS row

__device__ __forceinline__ int refl(int i, int n) {
    // BORDER_REFLECT_101: -1 -> 1, n -> n-2
    return i < 0 ? -i : (i >= n ? 2 * n - 2 - i : i);
}

// 10 stencil columns (x0-1 .. x0+8) from a 16-byte window starting at x0-4.
__device__ __forceinline__ void cols10(uint2 lo, uint2 hi, float* __restrict__ c) {
    c[0] = (float)(lo.x >> 24);
    c[1] = (float)(lo.y & 0xffu);
    c[2] = (float)((lo.y >> 8) & 0xffu);
    c[3] = (float)((lo.y >> 16) & 0xffu);
    c[4] = (float)(lo.y >> 24);
    c[5] = (float)(hi.x & 0xffu);
    c[6] = (float)((hi.x >> 8) & 0xffu);
    c[7] = (float)((hi.x >> 16) & 0xffu);
    c[8] = (float)(hi.x >> 24);
    c[9] = (float)(hi.y & 0xffu);
}

// ---------------- K1: fused gray + sobel + per-image min/max + q emit ----------------
// block = 256 threads, owns 8 rows of ONE source of one image.
__global__ __launch_bounds__(256) void k_sal(const float* __restrict__ vis,
                                             const float* __restrict__ ir,
                                             uint8_t* __restrict__ qvis,
                                             uint8_t* __restrict__ qir,
                                             uint32_t* __restrict__ mnmx, int B) {
    __shared__ uint8_t g[NSLOT][LSTR];
    __shared__ float red[4][2];
    int tid = threadIdx.x;
    int per_src = B * (H / TR);          // 1024
    int blk = blockIdx.x;
    int src = blk >= per_src;
    int rem = src ? blk - per_src : blk;
    int b  = rem >> 6;                   // H/TR = 64 strips per image
    int y0 = (rem & 63) * TR;

    const float4* p4 = (const float4*)((src ? ir : vis) + (size_t)b * 3 * HW);
    uint8_t* q = (src ? qir : qvis) + (size_t)b * HW;

    // Phase 1a: issue ALL 15 loads (5 tasks x 3 channels) before any use.
    // tasks: 10 slots x 128 float4-segs = 1280; 5 per thread.
    float4 R[5], G[5], Bl[5];
    #pragma unroll
    for (int it = 0; it < 5; ++it) {
        int t = tid + it * 256;
        int j = t >> 7, seg = t & 127;
        int row = refl(y0 - 1 + j, H);
        int o = row * (W / 4) + seg;
        R[it]  = p4[o];
        G[it]  = p4[o + HW / 4];
        Bl[it] = p4[o + 2 * (HW / 4)];
    }
    // Pin the boundary: loads above may NOT be sunk below this point, so all
    // 15 vmem ops are in flight together (one latency round, not five).
    __builtin_amdgcn_sched_barrier(0);
    // Phase 1b: gray + quantize + LDS write.
    #pragma unroll
    for (int it = 0; it < 5; ++it) {
        int t = tid + it * 256;
        int j = t >> 7, seg = t & 127;
        uchar4 qq;
        qq.x = (uint8_t)((0.2989f * R[it].x + 0.587f * G[it].x + 0.114f * Bl[it].x) * 255.0f);
        qq.y = (uint8_t)((0.2989f * R[it].y + 0.587f * G[it].y + 0.114f * Bl[it].y) * 255.0f);
        qq.z = (uint8_t)((0.2989f * R[it].z + 0.587f * G[it].z + 0.114f * Bl[it].z) * 255.0f);
        qq.w = (uint8_t)((0.2989f * R[it].w + 0.587f * G[it].w + 0.114f * Bl[it].w) * 255.0f);
        *(uchar4*)&g[j][4 + seg * 4] = qq;
    }
    __syncthreads();
    // reflect-101 column pads: byte 3 is x=-1 -> gray[1]; byte 516 is x=512 -> gray[510]
    if (tid < NSLOT) {
        g[tid][3]   = g[tid][5];    // 4+1
        g[tid][516] = g[tid][514];  // 4+510
    }
    __syncthreads();

    // Phase 2: sobel on core rows from LDS + q writeback + min/max.
    // tasks: 8 rows x 64 segs = 512; 2 per thread.
    float mn = INFINITY, mx = 0.0f;
    #pragma unroll
    for (int k = 0; k < 2; ++k) {
        int task = tid + k * 256;
        int r  = task >> 6;   // 0..7 -> slots r, r+1, r+2
        int s8 = task & 63;   // 8-px segment
        const uint8_t* rp0 = &g[r][s8 * 8];
        const uint8_t* rp1 = &g[r + 1][s8 * 8];
        const uint8_t* rp2 = &g[r + 2][s8 * 8];
        uint2 a0 = *(const uint2*)rp0, b0 = *(const uint2*)(rp0 + 8);
        uint2 a1 = *(const uint2*)rp1, b1 = *(const uint2*)(rp1 + 8);
        uint2 a2 = *(const uint2*)rp2, b2 = *(const uint2*)(rp2 + 8);
        // q writeback: image row y0+r bytes s8*8..+7 = window bytes 4..11 of center row
        uint2 qw; qw.x = a1.y; qw.y = b1.x;
        *(uint2*)(q + (size_t)(y0 + r) * W + s8 * 8) = qw;
        float c0[10], c1[10], c2[10];
        cols10(a0, b0, c0);
        cols10(a1, b1, c1);
        cols10(a2, b2, c2);
        float sx[10], sy[10];
        #pragma unroll
        for (int j = 0; j < 10; ++j) {
            sx[j] = c0[j] + 2.0f * c1[j] + c2[j];
            sy[j] = c2[j] - c0[j];
        }
        #pragma unroll
        for (int p = 0; p < 8; ++p) {
            float gx = sx[p + 2] - sx[p];
            float gy = sy[p] + 2.0f * sy[p + 1] + sy[p + 2];
            float m = sqrtf(gx * gx + gy * gy);
            mn = fminf(mn, m);
            mx = fmaxf(mx, m);
        }
    }

    // block reduce + atomics
    #pragma unroll
    for (int o = 32; o > 0; o >>= 1) {
        mn = fminf(mn, __shfl_down(mn, o));
        mx = fmaxf(mx, __shfl_down(mx, o));
    }
    int lane = tid & 63, w = tid >> 6;
    if (lane == 0) { red[w][0] = mn; red[w][1] = mx; }
    __syncthreads();
    if (tid == 0) {
        #pragma unroll
        for (int ww = 1; ww < 4; ++ww) {
            mn = fminf(mn, red[ww][0]);
            mx = fmaxf(mx, red[ww][1]);
        }
        // slots memset to 0xFFFFFFFF; max stored complemented so atomicMin works for both
        atomicMin(&mnmx[(src * B + b) * 2 + 0], __float_as_uint(mn));
        atomicMin(&mnmx[(src * B + b) * 2 + 1], ~__float_as_uint(mx));
    }
}

// Extract this lane's 10 stencil columns from an 8-byte row segment via shuffles.
__device__ __forceinline__ void row_cols(uint2 v, int lane, float* __restrict__ c) {
    uint32_t lx = __shfl_up(v.y, 1);
    uint32_t rx = __shfl_down(v.x, 1);
    uint32_t lb = (lane == 0)  ? ((v.x >> 8) & 0xffu)  : (lx >> 24);
    uint32_t rb = (lane == 63) ? ((v.y >> 16) & 0xffu) : (rx & 0xffu);
    c[0] = (float)lb;
    c[1] = (float)(v.x & 0xffu);
    c[2] = (float)((v.x >> 8) & 0xffu);
    c[3] = (float)((v.x >> 16) & 0xffu);
    c[4] = (float)(v.x >> 24);
    c[5] = (float)(v.y & 0xffu);
    c[6] = (float)((v.y >> 8) & 0xffu);
    c[7] = (float)((v.y >> 16) & 0xffu);
    c[8] = (float)(v.y >> 24);
    c[9] = (float)rb;
}

__device__ __forceinline__ void sobel_row8(const uint8_t* __restrict__ q, int y, int lane,
                                           float* __restrict__ mag) {
    const uint2* rm = (const uint2*)(q + (size_t)refl(y - 1, H) * W);
    const uint2* r0 = (const uint2*)(q + (size_t)y * W);
    const uint2* rp = (const uint2*)(q + (size_t)refl(y + 1, H) * W);
    uint2 vm = rm[lane], v0 = r0[lane], vp = rp[lane];
    float c0[10], c1[10], c2[10];
    row_cols(vm, lane, c0);
    row_cols(v0, lane, c1);
    row_cols(vp, lane, c2);
    float sx[10], sy[10];
    #pragma unroll
    for (int j = 0; j < 10; ++j) {
        sx[j] = c0[j] + 2.0f * c1[j] + c2[j];
        sy[j] = c2[j] - c0[j];
    }
    #pragma unroll
    for (int k = 0; k < 8; ++k) {
        float gx = sx[k + 2] - sx[k];
        float gy = sy[k] + 2.0f * sy[k + 1] + sy[k + 2];
        mag[k] = sqrtf(gx * gx + gy * gy);
    }
}

// ---------------- K2: weighted blend + |diff| partial sums ----------------
// block = 4 waves; each wave handles rows y0+w and y0+w+4 (8 rows per block)
__global__ __launch_bounds__(256) void k_loss(const float* __restrict__ vis,
                                              const float* __restrict__ ir,
                                              const float* __restrict__ fus,
                                              const uint8_t* __restrict__ qvis,
                                              const uint8_t* __restrict__ qir,
                                              const uint32_t* __restrict__ mnmx,
                                              float* __restrict__ partial, int B) {
    int w = threadIdx.x >> 6, lane = threadIdx.x & 63;
    int b = blockIdx.x >> 6;
    int y0 = (blockIdx.x & 63) * 8;

    float mn_v = __uint_as_float(mnmx[(0 * B + b) * 2 + 0]);
    float mx_v = __uint_as_float(~mnmx[(0 * B + b) * 2 + 1]);
    float mn_i = __uint_as_float(mnmx[(1 * B + b) * 2 + 0]);
    float mx_i = __uint_as_float(~mnmx[(1 * B + b) * 2 + 1]);
    float inv_v = 1.0f / fmaxf(mx_v - mn_v, 1e-8f);
    float inv_i = 1.0f / fmaxf(mx_i - mn_i, 1e-8f);

    float acc = 0.0f;
    #pragma unroll
    for (int rr = 0; rr < 2; ++rr) {
        int y = y0 + w + rr * 4;
        float mv[8], mi[8];
        sobel_row8(qvis + (size_t)b * HW, y, lane, mv);
        sobel_row8(qir  + (size_t)b * HW, y, lane, mi);

        float wv[8], wi[8];
        #pragma unroll
        for (int k = 0; k < 8; ++k) {
            float sv = (mv[k] - mn_v) * inv_v;
            float si = (mi[k] - mn_i) * inv_i;
            float den = sv + si + 1e-8f;
            float rden = 1.0f / den;
            wv[k] = sv * rden;
            wi[k] = si * rden;
        }

        int i = y * W + lane * 8;
        #pragma unroll
        for (int ch = 0; ch < 3; ++ch) {
            size_t e4 = ((((size_t)b * 3 + ch) * HW) + i) >> 2;
            const float4* v4 = (const float4*)vis;
            const float4* r4 = (const float4*)ir;
            const float4* f4 = (const float4*)fus;
            float4 va = v4[e4], vb = v4[e4 + 1];
            float4 ra = r4[e4], rb = r4[e4 + 1];
            float4 fa = f4[e4], fb = f4[e4 + 1];
            acc += fabsf(wv[0] * va.x + wi[0] * ra.x - fa.x);
            acc += fabsf(wv[1] * va.y + wi[1] * ra.y - fa.y);
            acc += fabsf(wv[2] * va.z + wi[2] * ra.z - fa.z);
            acc += fabsf(wv[3] * va.w + wi[3] * ra.w - fa.w);
            acc += fabsf(wv[4] * vb.x + wi[4] * rb.x - fb.x);
            acc += fabsf(wv[5] * vb.y + wi[5] * rb.y - fb.y);
            acc += fabsf(wv[6] * vb.z + wi[6] * rb.z - fb.z);
            acc += fabsf(wv[7] * vb.w + wi[7] * rb.w - fb.w);
        }
    }

    #pragma unroll
    for (int o = 32; o > 0; o >>= 1) acc += __shfl_down(acc, o);
    __shared__ float ssum[4];
    if (lane == 0) ssum[w] = acc;
    __syncthreads();
    if (threadIdx.x == 0) partial[blockIdx.x] = ssum[0] + ssum[1] + ssum[2] + ssum[3];
}

// ---------------- K3: final reduce ----------------
__global__ void k_final(const float* __restrict__ partial, int n, float* __restrict__ out,
                        long long N) {
    double s = 0.0;
    for (int i = threadIdx.x; i < n; i += 256) s += (double)partial[i];
    __shared__ double sm[256];
    sm[threadIdx.x] = s;
    __syncthreads();
    for (int k = 128; k > 0; k >>= 1) {
        if (threadIdx.x < k) sm[threadIdx.x] += sm[threadIdx.x + k];
        __syncthreads();
    }
    if (threadIdx.x == 0) out[0] = (float)(sm[0] / (double)N);
}

extern "C" void kernel_launch(void* const* d_in, const int* in_sizes, int n_in,
                              void* d_out, int out_size, void* d_ws, size_t ws_size,
                              hipStream_t stream) {
    const float* vis = (const float*)d_in[0];
    const float* ir  = (const float*)d_in[1];
    const float* fus = (const float*)d_in[2];
    int B = in_sizes[0] / (3 * HW);  // 16

    uint8_t* qvis = (uint8_t*)d_ws;
    uint8_t* qir  = qvis + (size_t)B * HW;
    uint32_t* mnmx = (uint32_t*)(qir + (size_t)B * HW);
    float* partial = (float*)(mnmx + 4 * B);
    float* out = (float*)d_out;

    // all-ones init: min slots use atomicMin(bits), max slots atomicMin(~bits)
    hipMemsetAsync(mnmx, 0xFF, (size_t)4 * B * sizeof(uint32_t), stream);

    int nblk_sal = 2 * B * (H / TR); // 2048 blocks, one source each
    k_sal<<<nblk_sal, 256, 0, stream>>>(vis, ir, qvis, qir, mnmx, B);

    int nblk_loss = B * (H / 8);     // 1024 blocks
    k_loss<<<nblk_loss, 256, 0, stream>>>(vis, ir, fus, qvis, qir, mnmx, partial, B);

    k_final<<<1, 256, 0, stream>>>(partial, nblk_loss, out, (long long)B * 3 * HW);
}

// Round 6
// 55.197 us; speedup vs baseline: 2.3678x; 1.3178x over previous
//
#include <hip/hip_runtime.h>
#include <hip/hip_bf16.h>
#include <stdint.h>

#define H 512
#define W 512
#define HW (H * W)
#define TR 8            // core rows per k_sal block
#define NSTRIP (H / TR) // 64 strips per image
#define NSLOT (TR + 2)  // core + 2 halo rows
#define LSTR 520        // 4 pad + 512 + 4 pad bytes per LDS row

__device__ __forceinline__ int refl(int i, int n) {
    // BORDER_REFLECT_101: -1 -> 1, n -> n-2
    return i < 0 ? -i : (i >= n ? 2 * n - 2 - i : i);
}

// 10 stencil columns (x0-1 .. x0+8) from a 16-byte window starting at x0-4.
__device__ __forceinline__ void cols10(uint2 lo, uint2 hi, float* __restrict__ c) {
    c[0] = (float)(lo.x >> 24);
    c[1] = (float)(lo.y & 0xffu);
    c[2] = (float)((lo.y >> 8) & 0xffu);
    c[3] = (float)((lo.y >> 16) & 0xffu);
    c[4] = (float)(lo.y >> 24);
    c[5] = (float)(hi.x & 0xffu);
    c[6] = (float)((hi.x >> 8) & 0xffu);
    c[7] = (float)((hi.x >> 16) & 0xffu);
    c[8] = (float)(hi.x >> 24);
    c[9] = (float)(hi.y & 0xffu);
}

// ---------------- K1: fused gray + sobel + per-strip min/max + q emit ----------------
// block = 256 threads, owns 8 rows of ONE source of one image.
// NO atomics: per-strip (mn,mx) goes to pm[] via a plain store.
__global__ __launch_bounds__(256) void k_sal(const float* __restrict__ vis,
                                             const float* __restrict__ ir,
                                             uint8_t* __restrict__ qvis,
                                             uint8_t* __restrict__ qir,
                                             float* __restrict__ pm, int B) {
    __shared__ uint8_t g[NSLOT][LSTR];
    __shared__ float red[4][2];
    int tid = threadIdx.x;
    int per_src = B * NSTRIP;            // 1024
    int blk = blockIdx.x;
    int src = blk >= per_src;
    int rem = src ? blk - per_src : blk;
    int b     = rem >> 6;
    int strip = rem & 63;
    int y0 = strip * TR;

    const float4* p4 = (const float4*)((src ? ir : vis) + (size_t)b * 3 * HW);
    uint8_t* q = (src ? qir : qvis) + (size_t)b * HW;

    // Phase 1a: issue ALL 15 loads (5 tasks x 3 channels) before any use.
    float4 R[5], G[5], Bl[5];
    #pragma unroll
    for (int it = 0; it < 5; ++it) {
        int t = tid + it * 256;
        int j = t >> 7, seg = t & 127;
        int row = refl(y0 - 1 + j, H);
        int o = row * (W / 4) + seg;
        R[it]  = p4[o];
        G[it]  = p4[o + HW / 4];
        Bl[it] = p4[o + 2 * (HW / 4)];
    }
    __builtin_amdgcn_sched_barrier(0);
    // Phase 1b: gray + quantize + LDS write.
    #pragma unroll
    for (int it = 0; it < 5; ++it) {
        int t = tid + it * 256;
        int j = t >> 7, seg = t & 127;
        uchar4 qq;
        qq.x = (uint8_t)((0.2989f * R[it].x + 0.587f * G[it].x + 0.114f * Bl[it].x) * 255.0f);
        qq.y = (uint8_t)((0.2989f * R[it].y + 0.587f * G[it].y + 0.114f * Bl[it].y) * 255.0f);
        qq.z = (uint8_t)((0.2989f * R[it].z + 0.587f * G[it].z + 0.114f * Bl[it].z) * 255.0f);
        qq.w = (uint8_t)((0.2989f * R[it].w + 0.587f * G[it].w + 0.114f * Bl[it].w) * 255.0f);
        *(uchar4*)&g[j][4 + seg * 4] = qq;
    }
    __syncthreads();
    // reflect-101 column pads: byte 3 is x=-1 -> gray[1]; byte 516 is x=512 -> gray[510]
    if (tid < NSLOT) {
        g[tid][3]   = g[tid][5];    // 4+1
        g[tid][516] = g[tid][514];  // 4+510
    }
    __syncthreads();

    // Phase 2: sobel on core rows from LDS + q writeback + min/max.
    float mn = INFINITY, mx = 0.0f;
    #pragma unroll
    for (int k = 0; k < 2; ++k) {
        int task = tid + k * 256;
        int r  = task >> 6;   // 0..7 -> slots r, r+1, r+2
        int s8 = task & 63;   // 8-px segment
        const uint8_t* rp0 = &g[r][s8 * 8];
        const uint8_t* rp1 = &g[r + 1][s8 * 8];
        const uint8_t* rp2 = &g[r + 2][s8 * 8];
        uint2 a0 = *(const uint2*)rp0, b0 = *(const uint2*)(rp0 + 8);
        uint2 a1 = *(const uint2*)rp1, b1 = *(const uint2*)(rp1 + 8);
        uint2 a2 = *(const uint2*)rp2, b2 = *(const uint2*)(rp2 + 8);
        uint2 qw; qw.x = a1.y; qw.y = b1.x;
        *(uint2*)(q + (size_t)(y0 + r) * W + s8 * 8) = qw;
        float c0[10], c1[10], c2[10];
        cols10(a0, b0, c0);
        cols10(a1, b1, c1);
        cols10(a2, b2, c2);
        float sx[10], sy[10];
        #pragma unroll
        for (int j = 0; j < 10; ++j) {
            sx[j] = c0[j] + 2.0f * c1[j] + c2[j];
            sy[j] = c2[j] - c0[j];
        }
        #pragma unroll
        for (int p = 0; p < 8; ++p) {
            float gx = sx[p + 2] - sx[p];
            float gy = sy[p] + 2.0f * sy[p + 1] + sy[p + 2];
            float m = sqrtf(gx * gx + gy * gy);
            mn = fminf(mn, m);
            mx = fmaxf(mx, m);
        }
    }

    // block reduce + plain store (no atomics, no contention)
    #pragma unroll
    for (int o = 32; o > 0; o >>= 1) {
        mn = fminf(mn, __shfl_down(mn, o));
        mx = fmaxf(mx, __shfl_down(mx, o));
    }
    int lane = tid & 63, w = tid >> 6;
    if (lane == 0) { red[w][0] = mn; red[w][1] = mx; }
    __syncthreads();
    if (tid == 0) {
        #pragma unroll
        for (int ww = 1; ww < 4; ++ww) {
            mn = fminf(mn, red[ww][0]);
            mx = fmaxf(mx, red[ww][1]);
        }
        float* o = pm + ((size_t)(src * B + b) * NSTRIP + strip) * 2;
        o[0] = mn;
        o[1] = mx;
    }
}

// Extract this lane's 10 stencil columns from an 8-byte row segment via shuffles.
__device__ __forceinline__ void row_cols(uint2 v, int lane, float* __restrict__ c) {
    uint32_t lx = __shfl_up(v.y, 1);
    uint32_t rx = __shfl_down(v.x, 1);
    uint32_t lb = (lane == 0)  ? ((v.x >> 8) & 0xffu)  : (lx >> 24);
    uint32_t rb = (lane == 63) ? ((v.y >> 16) & 0xffu) : (rx & 0xffu);
    c[0] = (float)lb;
    c[1] = (float)(v.x & 0xffu);
    c[2] = (float)((v.x >> 8) & 0xffu);
    c[3] = (float)((v.x >> 16) & 0xffu);
    c[4] = (float)(v.x >> 24);
    c[5] = (float)(v.y & 0xffu);
    c[6] = (float)((v.y >> 8) & 0xffu);
    c[7] = (float)((v.y >> 16) & 0xffu);
    c[8] = (float)(v.y >> 24);
    c[9] = (float)rb;
}

__device__ __forceinline__ void sobel_row8(const uint8_t* __restrict__ q, int y, int lane,
                                           float* __restrict__ mag) {
    const uint2* rm = (const uint2*)(q + (size_t)refl(y - 1, H) * W);
    const uint2* r0 = (const uint2*)(q + (size_t)y * W);
    const uint2* rp = (const uint2*)(q + (size_t)refl(y + 1, H) * W);
    uint2 vm = rm[lane], v0 = r0[lane], vp = rp[lane];
    float c0[10], c1[10], c2[10];
    row_cols(vm, lane, c0);
    row_cols(v0, lane, c1);
    row_cols(vp, lane, c2);
    float sx[10], sy[10];
    #pragma unroll
    for (int j = 0; j < 10; ++j) {
        sx[j] = c0[j] + 2.0f * c1[j] + c2[j];
        sy[j] = c2[j] - c0[j];
    }
    #pragma unroll
    for (int k = 0; k < 8; ++k) {
        float gx = sx[k + 2] - sx[k];
        float gy = sy[k] + 2.0f * sy[k + 1] + sy[k + 2];
        mag[k] = sqrtf(gx * gx + gy * gy);
    }
}

// ---------------- K2: minmax finalize + weighted blend + |diff| partial sums ----------------
// block = 4 waves; prologue: wave w shuffle-reduces one of {mn_v,mx_v,mn_i,mx_i}
// from the 64 per-strip partials; then each wave handles rows y0+w and y0+w+4.
__global__ __launch_bounds__(256) void k_loss(const float* __restrict__ vis,
                                              const float* __restrict__ ir,
                                              const float* __restrict__ fus,
                                              const uint8_t* __restrict__ qvis,
                                              const uint8_t* __restrict__ qir,
                                              const float* __restrict__ pm,
                                              float* __restrict__ partial, int B) {
    int w = threadIdx.x >> 6, lane = threadIdx.x & 63;
    int b = blockIdx.x >> 6;
    int y0 = (blockIdx.x & 63) * 8;

    __shared__ float sred[4];
    {
        int src = w >> 1, qsel = w & 1;
        float v = pm[((size_t)(src * B + b) * NSTRIP + lane) * 2 + qsel];
        if (qsel == 0) {
            #pragma unroll
            for (int o = 32; o > 0; o >>= 1) v = fminf(v, __shfl_down(v, o));
        } else {
            #pragma unroll
            for (int o = 32; o > 0; o >>= 1) v = fmaxf(v, __shfl_down(v, o));
        }
        if (lane == 0) sred[w] = v;
    }
    __syncthreads();
    float mn_v = sred[0], mx_v = sred[1], mn_i = sred[2], mx_i = sred[3];
    float inv_v = 1.0f / fmaxf(mx_v - mn_v, 1e-8f);
    float inv_i = 1.0f / fmaxf(mx_i - mn_i, 1e-8f);

    float acc = 0.0f;
    #pragma unroll
    for (int rr = 0; rr < 2; ++rr) {
        int y = y0 + w + rr * 4;
        float mv[8], mi[8];
        sobel_row8(qvis + (size_t)b * HW, y, lane, mv);
        sobel_row8(qir  + (size_t)b * HW, y, lane, mi);

        float wv[8], wi[8];
        #pragma unroll
        for (int k = 0; k < 8; ++k) {
            float sv = (mv[k] - mn_v) * inv_v;
            float si = (mi[k] - mn_i) * inv_i;
            float den = sv + si + 1e-8f;
            float rden = 1.0f / den;
            wv[k] = sv * rden;
            wi[k] = si * rden;
        }

        int i = y * W + lane * 8;
        #pragma unroll
        for (int ch = 0; ch < 3; ++ch) {
            size_t e4 = ((((size_t)b * 3 + ch) * HW) + i) >> 2;
            const float4* v4 = (const float4*)vis;
            const float4* r4 = (const float4*)ir;
            const float4* f4 = (const float4*)fus;
            float4 va = v4[e4], vb = v4[e4 + 1];
            float4 ra = r4[e4], rb = r4[e4 + 1];
            float4 fa = f4[e4], fb = f4[e4 + 1];
            acc += fabsf(wv[0] * va.x + wi[0] * ra.x - fa.x);
            acc += fabsf(wv[1] * va.y + wi[1] * ra.y - fa.y);
            acc += fabsf(wv[2] * va.z + wi[2] * ra.z - fa.z);
            acc += fabsf(wv[3] * va.w + wi[3] * ra.w - fa.w);
            acc += fabsf(wv[4] * vb.x + wi[4] * rb.x - fb.x);
            acc += fabsf(wv[5] * vb.y + wi[5] * rb.y - fb.y);
            acc += fabsf(wv[6] * vb.z + wi[6] * rb.z - fb.z);
            acc += fabsf(wv[7] * vb.w + wi[7] * rb.w - fb.w);
        }
    }

    #pragma unroll
    for (int o = 32; o > 0; o >>= 1) acc += __shfl_down(acc, o);
    __shared__ float ssum[4];
    if (lane == 0) ssum[w] = acc;
    __syncthreads();
    if (threadIdx.x == 0) partial[blockIdx.x] = ssum[0] + ssum[1] + ssum[2] + ssum[3];
}

// ---------------- K3: final reduce ----------------
__global__ void k_final(const float* __restrict__ partial, int n, float* __restrict__ out,
                        long long N) {
    double s = 0.0;
    for (int i = threadIdx.x; i < n; i += 256) s += (double)partial[i];
    __shared__ double sm[256];
    sm[threadIdx.x] = s;
    __syncthreads();
    for (int k = 128; k > 0; k >>= 1) {
        if (threadIdx.x < k) sm[threadIdx.x] += sm[threadIdx.x + k];
        __syncthreads();
    }
    if (threadIdx.x == 0) out[0] = (float)(sm[0] / (double)N);
}

extern "C" void kernel_launch(void* const* d_in, const int* in_sizes, int n_in,
                              void* d_out, int out_size, void* d_ws, size_t ws_size,
                              hipStream_t stream) {
    const float* vis = (const float*)d_in[0];
    const float* ir  = (const float*)d_in[1];
    const float* fus = (const float*)d_in[2];
    int B = in_sizes[0] / (3 * HW);  // 16

    uint8_t* qvis = (uint8_t*)d_ws;
    uint8_t* qir  = qvis + (size_t)B * HW;
    float* pm      = (float*)(qir + (size_t)B * HW);       // 2*B*64*2 floats
    float* partial = pm + (size_t)2 * B * NSTRIP * 2;      // 1024 floats
    float* out = (float*)d_out;

    int nblk_sal = 2 * B * NSTRIP;   // 2048 blocks, one source+strip each
    k_sal<<<nblk_sal, 256, 0, stream>>>(vis, ir, qvis, qir, pm, B);

    int nblk_loss = B * (H / 8);     // 1024 blocks
    k_loss<<<nblk_loss, 256, 0, stream>>>(vis, ir, fus, qvis, qir, pm, partial, B);

    k_final<<<1, 256, 0, stream>>>(partial, nblk_loss, out, (long long)B * 3 * HW);
}